// Round 1
// baseline (1983.114 us; speedup 1.0000x reference)
//
#include <hip/hip_runtime.h>
#include <hip/hip_bf16.h>
#include <stdint.h>

typedef __bf16 bf16_t;
typedef bf16_t bf16x8 __attribute__((ext_vector_type(8)));
typedef float  f32x4  __attribute__((ext_vector_type(4)));

// ---------------- async global->LDS (16B per lane) ----------------
__device__ __forceinline__ void g2l16(const void* gp, void* lp) {
  __builtin_amdgcn_global_load_lds(
      (const __attribute__((address_space(1))) unsigned int*)(uintptr_t)gp,
      (__attribute__((address_space(3))) unsigned int*)(uint32_t)(uintptr_t)lp,
      16, 0, 0);
}

// ---------------- embed: h[i] = x_emb1[x[i,0]] + x_emb2[x[i,1]] ----------------
__global__ void embed_kernel(const int* __restrict__ x, const float* __restrict__ e1,
                             const float* __restrict__ e2, bf16_t* __restrict__ h, int N) {
  const int w = (blockIdx.x * blockDim.x + threadIdx.x) >> 6;
  const int lane = threadIdx.x & 63;
  if (w >= N) return;
  const int t0 = x[2 * w], t1 = x[2 * w + 1];
  #pragma unroll
  for (int j = 0; j < 5; j++) {
    int col = lane + 64 * j;
    if (col < 300)
      h[(size_t)w * 320 + col] = (bf16_t)(e1[t0 * 300 + col] + e2[t1 * 300 + col]);
  }
}

// ---------------- CSR build ----------------
__global__ void count_deg_kernel(const int* __restrict__ ei, int* __restrict__ deg, int E) {
  int e = blockIdx.x * 256 + threadIdx.x;
  if (e < E) atomicAdd(&deg[ei[E + e]], 1);
}

__global__ void scan_partial_kernel(const int* __restrict__ deg, int* __restrict__ part, int N) {
  __shared__ int s[256];
  const int tid = threadIdx.x;
  const int idx = blockIdx.x * 256 + tid;
  s[tid] = (idx < N) ? deg[idx] : 0;
  __syncthreads();
  for (int off = 128; off > 0; off >>= 1) {
    if (tid < off) s[tid] += s[tid + off];
    __syncthreads();
  }
  if (tid == 0) part[blockIdx.x] = s[0];
}

__global__ void scan_block_kernel(int* __restrict__ part, int n) {  // n <= 1024
  __shared__ int s[1024];
  const int tid = threadIdx.x;
  const int v = (tid < n) ? part[tid] : 0;
  s[tid] = v;
  __syncthreads();
  for (int off = 1; off < 1024; off <<= 1) {
    int x = (tid >= off) ? s[tid - off] : 0;
    __syncthreads();
    s[tid] += x;
    __syncthreads();
  }
  if (tid < n) part[tid] = s[tid] - v;  // exclusive
}

__global__ void scan_final_kernel(const int* __restrict__ deg, const int* __restrict__ part,
                                  int* __restrict__ rowptr, int* __restrict__ cursor, int N, int E) {
  __shared__ int s[256];
  const int tid = threadIdx.x;
  const int idx = blockIdx.x * 256 + tid;
  const int v = (idx < N) ? deg[idx] : 0;
  s[tid] = v;
  __syncthreads();
  for (int off = 1; off < 256; off <<= 1) {
    int x = (tid >= off) ? s[tid - off] : 0;
    __syncthreads();
    s[tid] += x;
    __syncthreads();
  }
  if (idx < N) {
    int ex = s[tid] - v + part[blockIdx.x];
    rowptr[idx] = ex;
    cursor[idx] = ex;
  }
  if (idx == 0) rowptr[N] = E;
}

__global__ void fill_csr_kernel(const int* __restrict__ ei, const int* __restrict__ ea,
                                int* __restrict__ cursor, int* __restrict__ epack, int E) {
  int e = blockIdx.x * 256 + threadIdx.x;
  if (e >= E) return;
  int slot = atomicAdd(&cursor[ei[E + e]], 1);
  epack[slot] = (ei[e] & 0xFFFFF) | ((ea[2 * e] & 0xF) << 20) | ((ea[2 * e + 1] & 0xF) << 24);
}

// ---------------- weight convert+transpose+pad to bf16 ----------------
__global__ void convert_w1_kernel(const float* __restrict__ w1, bf16_t* __restrict__ o) {
  int id = blockIdx.x * 256 + threadIdx.x;
  if (id >= 5 * 640 * 320) return;
  int k = id % 320;
  int n = (id / 320) % 640;
  int l = id / (320 * 640);
  float v = (k < 300 && n < 600) ? w1[(size_t)l * 300 * 600 + (size_t)k * 600 + n] : 0.f;
  o[id] = (bf16_t)v;
}

__global__ void convert_w2_kernel(const float* __restrict__ w2, bf16_t* __restrict__ o) {
  int id = blockIdx.x * 256 + threadIdx.x;
  if (id >= 5 * 384 * 640) return;
  int k = id % 640;
  int n = (id / 640) % 384;
  int l = id / (640 * 384);
  float v = (k < 600 && n < 300) ? w2[(size_t)l * 600 * 300 + (size_t)k * 300 + n] : 0.f;
  o[id] = (bf16_t)v;
}

// ---------------- aggregation: wave per node, CSR gather ----------------
__global__ void aggregate_kernel(const bf16_t* __restrict__ h, const int* __restrict__ rowptr,
                                 const int* __restrict__ epack, const float* __restrict__ T1,
                                 const float* __restrict__ T2, bf16_t* __restrict__ agg, int N) {
  const int w = (blockIdx.x * blockDim.x + threadIdx.x) >> 6;
  const int lane = threadIdx.x & 63;
  if (w >= N) return;
  float acc[5];
  // self loop: h[i] + E1[4] + E2[0]
  #pragma unroll
  for (int j = 0; j < 5; j++) {
    int col = lane + 64 * j;
    acc[j] = 0.f;
    if (col < 300)
      acc[j] = (float)h[(size_t)w * 320 + col] + T1[4 * 300 + col] + T2[col];
  }
  const int beg = rowptr[w], end = rowptr[w + 1];
  for (int e = beg; e < end; e++) {
    const int p = epack[e];
    const int s = p & 0xFFFFF;
    const int a0 = (p >> 20) & 0xF;
    const int a1 = (p >> 24) & 0xF;
    const size_t sb = (size_t)s * 320;
    #pragma unroll
    for (int j = 0; j < 5; j++) {
      int col = lane + 64 * j;
      if (col < 300)
        acc[j] += (float)h[sb + col] + T1[a0 * 300 + col] + T2[a1 * 300 + col];
    }
  }
  #pragma unroll
  for (int j = 0; j < 5; j++) {
    int col = lane + 64 * j;
    if (col < 300) agg[(size_t)w * 320 + col] = (bf16_t)acc[j];
  }
}

// ---------------- m97-style bf16 MFMA GEMM, 128x128 tile, BK=32 ----------------
// C[m,n] = act( sum_k A[m,k] * BT[n,k] + bias[n] ),  all dims padded to tiles.
__global__ __launch_bounds__(256) void gemm_bf16_kernel(
    const bf16_t* __restrict__ A, const bf16_t* __restrict__ BT,
    const float* __restrict__ bias, bf16_t* __restrict__ C,
    int lda, int ldb, int ldc, int nk, int nbias, int relu) {
  __shared__ __align__(16) bf16_t As[128 * 32];
  __shared__ __align__(16) bf16_t Bs[128 * 32];

  const int tid = threadIdx.x;
  const int lane = tid & 63;
  const int wave = tid >> 6;
  const int wm = (wave & 1) * 64;
  const int wn = (wave >> 1) * 64;
  const int ml = lane & 15;
  const int quad = lane >> 4;
  const size_t bm = (size_t)blockIdx.x * 128;
  const size_t bnn = (size_t)blockIdx.y * 128;

  f32x4 acc[4][4];
  #pragma unroll
  for (int r = 0; r < 4; r++)
    #pragma unroll
    for (int c = 0; c < 4; c++) acc[r][c] = (f32x4){0.f, 0.f, 0.f, 0.f};

  const int r0 = tid >> 2;          // 0..63
  const int k0 = (tid & 3) * 8;     // 0,8,16,24
  const int r1 = r0 + 64;           // 64..127

  for (int kb = 0; kb < nk; kb++) {
    const int kbase = kb * 32 + k0;
    g2l16(A + (bm + r0) * lda + kbase, (void*)&As[(size_t)tid * 8]);
    g2l16(A + (bm + r1) * lda + kbase, (void*)&As[((size_t)tid + 256) * 8]);
    g2l16(BT + (bnn + r0) * ldb + kbase, (void*)&Bs[(size_t)tid * 8]);
    g2l16(BT + (bnn + r1) * ldb + kbase, (void*)&Bs[((size_t)tid + 256) * 8]);
    __syncthreads();  // compiler drains vmcnt before barrier -> LDS ready

    bf16x8 aF[4], bF[4];
    #pragma unroll
    for (int r = 0; r < 4; r++)
      aF[r] = *(const bf16x8*)&As[(wm + r * 16 + ml) * 32 + quad * 8];
    #pragma unroll
    for (int c = 0; c < 4; c++)
      bF[c] = *(const bf16x8*)&Bs[(wn + c * 16 + ml) * 32 + quad * 8];
    #pragma unroll
    for (int r = 0; r < 4; r++)
      #pragma unroll
      for (int c = 0; c < 4; c++)
        acc[r][c] = __builtin_amdgcn_mfma_f32_16x16x32_bf16(aF[r], bF[c], acc[r][c], 0, 0, 0);
    __syncthreads();
  }

  // epilogue: C/D layout col=lane&15, row=quad*4+reg
  #pragma unroll
  for (int c = 0; c < 4; c++) {
    const int colg = (int)bnn + wn + c * 16 + ml;
    const float bv = (colg < nbias) ? bias[colg] : 0.f;
    #pragma unroll
    for (int r = 0; r < 4; r++) {
      #pragma unroll
      for (int i = 0; i < 4; i++) {
        const size_t rowg = bm + wm + r * 16 + quad * 4 + i;
        float v = acc[r][c][i] + bv;
        if (relu) v = fmaxf(v, 0.f);
        C[rowg * ldc + colg] = (bf16_t)v;
      }
    }
  }
}

// ---------------- BN ----------------
__global__ void bn_stats_kernel(const bf16_t* __restrict__ H2, float* __restrict__ sums,
                                float* __restrict__ sumsq, int N) {
  const int col = threadIdx.x;
  if (col >= 300) return;
  const int r0 = blockIdx.x * 128;
  const int r1 = (r0 + 128 < N) ? r0 + 128 : N;
  float s = 0.f, ss = 0.f;
  #pragma unroll 4
  for (int r = r0; r < r1; r++) {
    float v = (float)H2[(size_t)r * 384 + col];
    s += v;
    ss += v * v;
  }
  atomicAdd(&sums[col], s);
  atomicAdd(&sumsq[col], ss);
}

__global__ void bn_params_kernel(const float* __restrict__ sums, const float* __restrict__ sumsq,
                                 const float* __restrict__ gamma, const float* __restrict__ beta,
                                 float* __restrict__ scale, float* __restrict__ shift, int N) {
  const int col = threadIdx.x;
  if (col >= 300) return;
  const float inv = 1.f / (float)N;
  const float mean = sums[col] * inv;
  float var = sumsq[col] * inv - mean * mean;
  if (var < 0.f) var = 0.f;
  const float sc = gamma[col] * rsqrtf(var + 1e-5f);
  scale[col] = sc;
  shift[col] = beta[col] - mean * sc;
}

__global__ void bn_apply_kernel(const bf16_t* __restrict__ H2, const float* __restrict__ scale,
                                const float* __restrict__ shift, bf16_t* __restrict__ h,
                                float* __restrict__ out, int relu, int last) {
  const int row = blockIdx.x;
  const int col = threadIdx.x;
  if (col >= 300) return;
  float v = (float)H2[(size_t)row * 384 + col] * scale[col] + shift[col];
  if (relu) v = fmaxf(v, 0.f);
  if (last)
    out[(size_t)row * 300 + col] = v;
  else
    h[(size_t)row * 320 + col] = (bf16_t)v;
}

// ---------------- launch ----------------
extern "C" void kernel_launch(void* const* d_in, const int* in_sizes, int n_in,
                              void* d_out, int out_size, void* d_ws, size_t ws_size,
                              hipStream_t stream) {
  const int* x = (const int*)d_in[0];
  const int* ei = (const int*)d_in[1];
  const int* ea = (const int*)d_in[2];
  const float* xe1 = (const float*)d_in[3];
  const float* xe2 = (const float*)d_in[4];
  const float* ee1 = (const float*)d_in[5];
  const float* ee2 = (const float*)d_in[6];
  const float* w1 = (const float*)d_in[7];
  const float* b1 = (const float*)d_in[8];
  const float* w2 = (const float*)d_in[9];
  const float* b2 = (const float*)d_in[10];
  const float* gam = (const float*)d_in[11];
  const float* bet = (const float*)d_in[12];

  const int N = in_sizes[0] / 2;   // 100000
  const int E = in_sizes[1] / 2;   // 200000
  const int Mt = (N + 127) / 128;  // 782
  const size_t Mp = (size_t)Mt * 128;

  char* p = (char*)d_ws;
  auto take = [&](size_t b) -> char* {
    char* r = p;
    p += (b + 255) & ~(size_t)255;
    return r;
  };
  bf16_t* h    = (bf16_t*)take(Mp * 320 * 2);
  bf16_t* agg  = (bf16_t*)take(Mp * 320 * 2);
  bf16_t* C1   = (bf16_t*)take(Mp * 640 * 2);
  bf16_t* H2   = (bf16_t*)take(Mp * 384 * 2);
  bf16_t* W1bT = (bf16_t*)take((size_t)5 * 640 * 320 * 2);
  bf16_t* W2bT = (bf16_t*)take((size_t)5 * 384 * 640 * 2);
  int* deg     = (int*)take((size_t)N * 4);
  int* rowptr  = (int*)take((size_t)(N + 1) * 4);
  int* cursor  = (int*)take((size_t)N * 4);
  int* part    = (int*)take(1024 * 4);
  int* epack   = (int*)take((size_t)E * 4);
  float* sums  = (float*)take(384 * 4);
  float* sumsq = (float*)take(384 * 4);
  float* scale = (float*)take(384 * 4);
  float* shift = (float*)take(384 * 4);

  // zero pad regions of agg (GEMM1 reads pad rows/cols as exact zeros) and deg
  hipMemsetAsync(agg, 0, Mp * 320 * 2, stream);
  hipMemsetAsync(deg, 0, (size_t)N * 4, stream);

  const int nwb = (N + 3) / 4;  // wave-per-node, 4 waves per 256-thread block
  embed_kernel<<<nwb, 256, 0, stream>>>(x, xe1, xe2, h, N);

  count_deg_kernel<<<(E + 255) / 256, 256, 0, stream>>>(ei, deg, E);
  const int nsb = (N + 255) / 256;  // 391 (<=1024 required by scan_block)
  scan_partial_kernel<<<nsb, 256, 0, stream>>>(deg, part, N);
  scan_block_kernel<<<1, 1024, 0, stream>>>(part, nsb);
  scan_final_kernel<<<nsb, 256, 0, stream>>>(deg, part, rowptr, cursor, N, E);
  fill_csr_kernel<<<(E + 255) / 256, 256, 0, stream>>>(ei, ea, cursor, epack, E);

  convert_w1_kernel<<<(5 * 640 * 320 + 255) / 256, 256, 0, stream>>>(w1, W1bT);
  convert_w2_kernel<<<(5 * 384 * 640 + 255) / 256, 256, 0, stream>>>(w2, W2bT);

  for (int l = 0; l < 5; l++) {
    aggregate_kernel<<<nwb, 256, 0, stream>>>(h, rowptr, epack, ee1 + (size_t)l * 7 * 300,
                                              ee2 + (size_t)l * 3 * 300, agg, N);
    // GEMM1: [Mp,320] x W1T[640,320] -> C1[Mp,640], bias b1 (600), ReLU
    gemm_bf16_kernel<<<dim3(Mt, 5), 256, 0, stream>>>(agg, W1bT + (size_t)l * 640 * 320,
                                                      b1 + (size_t)l * 600, C1,
                                                      320, 320, 640, 10, 600, 1);
    // GEMM2: [Mp,640] x W2T[384,640] -> H2[Mp,384], bias b2 (300)
    gemm_bf16_kernel<<<dim3(Mt, 3), 256, 0, stream>>>(C1, W2bT + (size_t)l * 384 * 640,
                                                      b2 + (size_t)l * 300, H2,
                                                      640, 640, 384, 20, 300, 0);
    hipMemsetAsync(sums, 0, 384 * 4, stream);
    hipMemsetAsync(sumsq, 0, 384 * 4, stream);
    bn_stats_kernel<<<(N + 127) / 128, 320, 0, stream>>>(H2, sums, sumsq, N);
    bn_params_kernel<<<1, 320, 0, stream>>>(sums, sumsq, gam + (size_t)l * 300,
                                            bet + (size_t)l * 300, scale, shift, N);
    bn_apply_kernel<<<N, 320, 0, stream>>>(H2, scale, shift, h, (float*)d_out,
                                           (l < 4) ? 1 : 0, (l == 4) ? 1 : 0);
  }
}